// Round 5
// baseline (291.763 us; speedup 1.0000x reference)
//
#include <hip/hip_runtime.h>
#include <hip/hip_bf16.h>
#include <stdint.h>

// CRF loss (forward partition + gold path score), B=32, L=1024, D=1024, 66 tags.
// Pipeline (3 kernels):
//   crf_wcvt : fc_w [1024][66] fp32 -> Wbt [64][1024] bf16 (LDS-tiled transpose)
//   crf_fwd  : per (chunk c of 32 steps, batch b) block (1024 blocks, 4 waves):
//              (a) emission tile GEMM (32 rows x 64 tags) via bf16 MFMA,
//                  global_load_lds-staged, double-buffered, 1 barrier/K-tile
//              (b) 32-step chunk product of M_t = diag(exp(emit_t)).E as
//                  64x64 bf16 MFMA matmuls with per-step pow2 rescale
//              LDS arena (32KB) aliased between phases -> 4 blocks/CU.
//   crf_fin  : even blocks: per-batch combine (32 chained matvecs + STOP lse)
//              odd blocks:  gold path score (gathers)
//
// START/STOP tags are exact prob-0 (exp(-10000) underflows to 0 in f32, same
// as the reference) -> live state is exactly 64 tags = one wave lane each.

#define START_IDX 64
#define STOP_IDX 65
#define LN2F 0.6931471805599453f

typedef __attribute__((ext_vector_type(4))) float f32x4;
typedef __attribute__((ext_vector_type(8))) __bf16 bf16x8;
typedef __attribute__((ext_vector_type(4))) __bf16 bf16x4;

// async global->LDS, 16B per lane; dst = wave-uniform base + lane*16
__device__ __forceinline__ void gload_lds16(const void* g, void* l) {
  __builtin_amdgcn_global_load_lds(
      (const __attribute__((address_space(1))) void*)g,
      (__attribute__((address_space(3))) void*)l, 16, 0, 0);
}

// ------------------------------------------------------------------
// DPP helpers (full-wave reduce; result valid in lane 63; values >= 0)
// ------------------------------------------------------------------
template <int CTRL>
__device__ __forceinline__ float dpp_mov(float v) {
  return __int_as_float(
      __builtin_amdgcn_update_dpp(0, __float_as_int(v), CTRL, 0xF, 0xF, true));
}
__device__ __forceinline__ float wave_max64(float v) {
  v = fmaxf(v, dpp_mov<0xB1>(v));   // quad_perm xor1
  v = fmaxf(v, dpp_mov<0x4E>(v));   // quad_perm xor2
  v = fmaxf(v, dpp_mov<0x141>(v));  // row_half_mirror
  v = fmaxf(v, dpp_mov<0x140>(v));  // row_mirror
  v = fmaxf(v, dpp_mov<0x142>(v));  // row_bcast15
  v = fmaxf(v, dpp_mov<0x143>(v));  // row_bcast31
  return v;
}
__device__ __forceinline__ float wave_sum64(float v) {
  v += dpp_mov<0xB1>(v);
  v += dpp_mov<0x4E>(v);
  v += dpp_mov<0x141>(v);
  v += dpp_mov<0x140>(v);
  v += dpp_mov<0x142>(v);
  v += dpp_mov<0x143>(v);
  return v;
}

// ------------------------------------------------------------------
// W convert+transpose via LDS tile: Wbt[n][k] = bf16(W[k][n]), n<64, k<1024.
// ------------------------------------------------------------------
__global__ __launch_bounds__(256) void crf_wcvt(const float* __restrict__ W,
                                                unsigned short* __restrict__ Wbt) {
  __shared__ float tile[64][65];
  const int t = threadIdx.x;
  const int kb = blockIdx.x;  // k-slice of 64
#pragma unroll
  for (int i = 0; i < 16; ++i) {
    const int f = i * 256 + t;
    const int k = f >> 6, n = f & 63;
    tile[k][n] = W[(kb * 64 + k) * 66 + n];
  }
  __syncthreads();
#pragma unroll
  for (int i = 0; i < 16; ++i) {
    const int f = i * 256 + t;
    const int n = f >> 6, k = f & 63;
    union { __bf16 h; unsigned short u; } cv;
    cv.h = (__bf16)tile[k][n];
    Wbt[n * 1024 + kb * 64 + k] = cv.u;
  }
}

// ------------------------------------------------------------------
// Fused emission + chunk-product kernel. Grid (32 chunks, 32 batches), 4 waves.
// LDS arena (32KB), aliased:
//   GEMM: A0 [0,8K) A1 [8K,16K) B0 [16K,24K) B1 [24K,32K)
//   scan: expE [0,8K)  T[0] [16K,24K)  T[1] [24K,32K)
// ------------------------------------------------------------------
__global__ __launch_bounds__(256) void crf_fwd(const float* __restrict__ features,
                                               const unsigned short* __restrict__ Wbt,
                                               const float* __restrict__ bias,
                                               const float* __restrict__ masks,
                                               const float* __restrict__ trans,
                                               float* __restrict__ featsOut,
                                               float* __restrict__ chunkP,
                                               int* __restrict__ chunkExp) {
  __shared__ __align__(16) char smem[32768];
  __shared__ float wmax[2][4];
  const int tid = threadIdx.x;
  const int w = tid >> 6, lane = tid & 63, g = lane >> 4, q = lane & 15;
  const int c = blockIdx.x, b = blockIdx.y;   // 32 chunks x 32 batches
  const int rb = w & 1, cb = w >> 1;          // GEMM: wave = 16 rows x 32 cols

  const float* Abase = features + ((size_t)b << 20) + ((size_t)c << 15);

  // ---- (a) emission GEMM: rows t = c*32 + [0,32), cols = 64 tags ----
  {
    // staging lambdas (wave w stages 8 A-rows, 16 B-rows per K-tile)
    const int arow0 = 8 * w + (lane >> 4);         // +4j
    const int acolb = ((lane & 15) * 16);
    const int brow0 = 16 * w + (lane >> 3);        // +8j
    const int bcolb = ((lane & 7) * 16);

    f32x4 acc[2];
    acc[0] = (f32x4){0.f, 0.f, 0.f, 0.f};
    acc[1] = (f32x4){0.f, 0.f, 0.f, 0.f};

    // prologue: stage tile 0 into buf 0
#pragma unroll
    for (int j = 0; j < 2; ++j) {
      const int row = arow0 + 4 * j;
      gload_lds16((const char*)(Abase + (size_t)row * 1024) +
                      (acolb ^ ((row & 7) << 4)),
                  smem + (8 * w + 4 * j) * 256);
      const int n = brow0 + 8 * j;
      gload_lds16((const char*)(Wbt + (size_t)n * 1024) +
                      (bcolb ^ ((n & 7) << 4)),
                  smem + 16384 + (16 * w + 8 * j) * 128);
    }

    const int sA = (q & 7) << 4;
    for (int kt = 0; kt < 16; ++kt) {
      const int buf = kt & 1;
      __syncthreads();  // drains vmcnt: buf `buf` ready
      if (kt < 15) {    // prefetch next tile into other buffer
        const int k0 = (kt + 1) * 64;
#pragma unroll
        for (int j = 0; j < 2; ++j) {
          const int row = arow0 + 4 * j;
          gload_lds16((const char*)(Abase + (size_t)row * 1024 + k0) +
                          (acolb ^ ((row & 7) << 4)),
                      smem + (buf ^ 1) * 8192 + (8 * w + 4 * j) * 256);
          const int n = brow0 + 8 * j;
          gload_lds16((const char*)(Wbt + (size_t)n * 1024 + k0) +
                          (bcolb ^ ((n & 7) << 4)),
                      smem + 16384 + (buf ^ 1) * 8192 + (16 * w + 8 * j) * 128);
        }
      }
      const char* Ab = smem + buf * 8192 + (16 * rb + q) * 256;
      const char* Bb = smem + 16384 + buf * 8192;
#pragma unroll
      for (int kk = 0; kk < 2; ++kk) {
        float4 alo = *(const float4*)(Ab + ((kk * 128 + 32 * g) ^ sA));
        float4 ahi = *(const float4*)(Ab + ((kk * 128 + 32 * g + 16) ^ sA));
        bf16x8 af;
        af[0] = (__bf16)alo.x; af[1] = (__bf16)alo.y;
        af[2] = (__bf16)alo.z; af[3] = (__bf16)alo.w;
        af[4] = (__bf16)ahi.x; af[5] = (__bf16)ahi.y;
        af[6] = (__bf16)ahi.z; af[7] = (__bf16)ahi.w;
#pragma unroll
        for (int nt = 0; nt < 2; ++nt) {
          const int n = q + 16 * (2 * cb + nt);
          bf16x8 bf = *(const bf16x8*)(Bb + n * 128 +
                                       ((kk * 64 + 16 * g) ^ ((n & 7) << 4)));
          acc[nt] = __builtin_amdgcn_mfma_f32_16x16x32_bf16(af, bf, acc[nt], 0, 0, 0);
        }
      }
    }
    // After the kt=15 iteration every wave has passed the kt=15 barrier, so
    // all reads of buf0/A0/B0 regions are complete -> safe to write expE/T[0].
    const float bb0 = bias[q + 32 * cb], bb1 = bias[q + 32 * cb + 16];
    float (*expE)[64] = (float(*)[64])smem;
#pragma unroll
    for (int r = 0; r < 4; ++r) {
      const int tl = 16 * rb + 4 * g + r;  // local t within chunk
      float* orow = featsOut + (((size_t)(b << 10) + (c << 5) + tl) << 6) +
                    q + 32 * cb;
      const float v0 = acc[0][r] + bb0, v1 = acc[1][r] + bb1;
      orow[0] = v0; orow[16] = v1;
      expE[tl][q + 32 * cb] = __expf(v0);
      expE[tl][q + 32 * cb + 16] = __expf(v1);
    }
  }

  // ---- T[0] = identity (swizzled, in [16K,24K)) ----
  {
    char* T0 = smem + 16384;
    f32x4 z4 = {0.f, 0.f, 0.f, 0.f};
    *(f32x4*)(T0 + tid * 32) = z4;
    *(f32x4*)(T0 + tid * 32 + 16) = z4;
    const int n = tid >> 2, s = tid & 3;
    const int d = (2 * n) ^ ((n & 7) << 4);
    if ((d >> 5) == s)
      *(unsigned short*)(T0 + n * 128 + d) = (unsigned short)0x3F80;
    if (tid < 4) wmax[0][tid] = 1.0f;
  }

  // ---- (b) chunk scan ----
  bf16x8 Ea0, Ea1;  // E fragments (A operand): rows i = 16w+q
  {
    const int i = 16 * w + q;
    const float* tp0 = trans + i * 66 + 8 * g;
    const float* tp1 = tp0 + 32;
#pragma unroll
    for (int e = 0; e < 8; ++e) {
      Ea0[e] = (__bf16)__expf(tp0[e]);
      Ea1[e] = (__bf16)__expf(tp1[e]);
    }
  }

  float pv[4][4];  // fp32 copy of P: row 16w+4g+r, col q+16nt
#pragma unroll
  for (int nt = 0; nt < 4; ++nt)
#pragma unroll
    for (int r = 0; r < 4; ++r)
      pv[nt][r] = ((16 * w + 4 * g + r) == (q + 16 * nt)) ? 1.f : 0.f;

  const int t0 = (c == 0) ? 1 : (c << 5);
  const int t1 = (c << 5) + 32;
  const float* mb = masks + (b << 10);
  const int tml = t0 + lane;
  const float mkv = mb[tml > 1023 ? 1023 : tml];
  float (*expE)[64] = (float(*)[64])smem;

  int e_acc = 0;
  int cur = 0;
  __syncthreads();  // T[0], expE ready

  for (int t = t0; t < t1; ++t) {
    const int tl = t - (c << 5);
    const float4 ee = *(const float4*)&expE[tl][16 * w + 4 * g];  // exp(emit_t)
    const float m =
        __int_as_float(__builtin_amdgcn_readlane(__float_as_int(mkv), t - t0));
    if (m != 0.f) {
      const char* Tb = smem + 16384 + cur * 8192;
      f32x4 acc[4];
#pragma unroll
      for (int nt = 0; nt < 4; ++nt) {
        const int n = q + 16 * nt;
        const int sw = (n & 7) << 4;
        bf16x8 B0 = *(const bf16x8*)(Tb + n * 128 + ((16 * g) ^ sw));
        bf16x8 B1 = *(const bf16x8*)(Tb + n * 128 + ((64 + 16 * g) ^ sw));
        f32x4 z = {0.f, 0.f, 0.f, 0.f};
        z = __builtin_amdgcn_mfma_f32_16x16x32_bf16(Ea0, B0, z, 0, 0, 0);
        acc[nt] = __builtin_amdgcn_mfma_f32_16x16x32_bf16(Ea1, B1, z, 0, 0, 0);
      }
      const float4 wm = *(const float4*)wmax[cur];
      const float mx = fmaxf(fmaxf(wm.x, wm.y), fmaxf(wm.z, wm.w));
      const int ex = ((__float_as_int(mx) >> 23) & 0xFF) - 127;
      const float sc = __int_as_float((127 - ex) << 23);
      float ce[4];
      ce[0] = ee.x * sc; ce[1] = ee.y * sc; ce[2] = ee.z * sc; ce[3] = ee.w * sc;
      float nmax[4];
#pragma unroll
      for (int nt = 0; nt < 4; ++nt) {
#pragma unroll
        for (int r = 0; r < 4; ++r) {
          float val = acc[nt][r] * ce[r];
          if (m != 1.f) val = m * val + (1.f - m) * sc * pv[nt][r];
          pv[nt][r] = val;
        }
        nmax[nt] = fmaxf(fmaxf(pv[nt][0], pv[nt][1]),
                         fmaxf(pv[nt][2], pv[nt][3]));
      }
      const int nxt = cur ^ 1;
      char* Tw = smem + 16384 + nxt * 8192;
#pragma unroll
      for (int nt = 0; nt < 4; ++nt) {
        bf16x4 o;
        o[0] = (__bf16)pv[nt][0]; o[1] = (__bf16)pv[nt][1];
        o[2] = (__bf16)pv[nt][2]; o[3] = (__bf16)pv[nt][3];
        const int n = q + 16 * nt;
        *(bf16x4*)(Tw + n * 128 + ((32 * w + 8 * g) ^ ((n & 7) << 4))) = o;
      }
      float lm = wave_max64(fmaxf(fmaxf(nmax[0], nmax[1]),
                                  fmaxf(nmax[2], nmax[3])));
      if (lane == 63) wmax[nxt][w] = lm;
      e_acc += ex;
      __syncthreads();
      cur = nxt;
    }
  }

  // epilogue: write P (fp32) + exponent
#pragma unroll
  for (int nt = 0; nt < 4; ++nt)
#pragma unroll
    for (int r = 0; r < 4; ++r)
      chunkP[(((size_t)(b * 32 + c)) << 12) + (size_t)(16 * w + 4 * g + r) * 64 +
             q + 16 * nt] = pv[nt][r];
  if (tid == 0) chunkExp[b * 32 + c] = e_acc;
}

// ------------------------------------------------------------------
// Final kernel: even blocks -> combine (forward score), odd -> gold score.
// ------------------------------------------------------------------
__global__ void crf_fin(const float* __restrict__ feats,
                        const int* __restrict__ ys,
                        const float* __restrict__ masks,
                        const float* __restrict__ trans,
                        const float* __restrict__ chunkP,
                        const int* __restrict__ chunkExp,
                        float* __restrict__ out) {
  __shared__ __align__(16) float vb[64];
  const int lane = threadIdx.x;
  const int b = blockIdx.x >> 1;
  if ((blockIdx.x & 1) == 0) {
    // ---- combine: v <- Pc . v over 32 chunks, then STOP logsumexp ----
    float v = __expf(feats[((size_t)b << 16) + lane]) *
              __expf(trans[lane * 66 + START_IDX]);
    int e_acc = 0;
    for (int cc = 0; cc < 32; ++cc) {
      vb[lane] = v;
      __builtin_amdgcn_wave_barrier();
      const float* Pr = chunkP + (((size_t)(b * 32 + cc)) << 12) + (size_t)lane * 64;
      float q0 = 0.f, q1 = 0.f, q2 = 0.f, q3 = 0.f;
#pragma unroll
      for (int j4 = 0; j4 < 16; ++j4) {
        float4 p = *(const float4*)(Pr + 4 * j4);
        float4 x = ((const float4*)vb)[j4];
        q0 = fmaf(p.x, x.x, q0); q1 = fmaf(p.y, x.y, q1);
        q2 = fmaf(p.z, x.z, q2); q3 = fmaf(p.w, x.w, q3);
      }
      const float qq = (q0 + q1) + (q2 + q3);
      float mx = wave_max64(qq);
      mx = __int_as_float(__builtin_amdgcn_readlane(__float_as_int(mx), 63));
      const int ex = ((__float_as_int(mx) >> 23) & 0xFF) - 127;
      v = qq * __int_as_float((127 - ex) << 23);
      e_acc += ex + chunkExp[b * 32 + cc];
      __builtin_amdgcn_wave_barrier();
    }
    const float sum = wave_sum64(v * __expf(trans[STOP_IDX * 66 + lane]));
    const float s =
        __int_as_float(__builtin_amdgcn_readlane(__float_as_int(sum), 63));
    if (lane == 0) out[b] = __logf(s) + (float)e_acc * LN2F;
  } else {
    // ---- gold path score ----
    const float* fb = feats + ((size_t)b << 16);
    const float* mb = masks + (b << 10);
    const int* yb = ys + (b << 10);
    float s = 0.f, cnt = 0.f;
#pragma unroll
    for (int cc = 0; cc < 16; ++cc) {
      const int t = cc * 64 + lane;
      const float m = mb[t];
      const int y = yb[t];
      const int yp = (t == 0) ? START_IDX : yb[t - 1];
      s += (trans[y * 66 + yp] + fb[t * 64 + y]) * m;
      cnt += m;
    }
    float tot = wave_sum64(s);
    float len = wave_sum64(cnt);
    int totb = __builtin_amdgcn_readlane(__float_as_int(tot), 63);
    int lenb = __builtin_amdgcn_readlane(__float_as_int(len), 63);
    if (lane == 0) {
      const int Lr = (int)__int_as_float(lenb);
      const int last = (Lr == 0) ? START_IDX : yb[Lr - 1];
      out[32 + b] = __int_as_float(totb) + trans[STOP_IDX * 66 + last];
    }
  }
}

// ------------------------------------------------------------------
extern "C" void kernel_launch(void* const* d_in, const int* in_sizes, int n_in,
                              void* d_out, int out_size, void* d_ws, size_t ws_size,
                              hipStream_t stream) {
  const float* features = (const float*)d_in[0];   // [32][1024][1024]
  const int* ys         = (const int*)d_in[1];     // [32][1024]
  const float* masks    = (const float*)d_in[2];   // [32][1024]
  const float* fc_w     = (const float*)d_in[3];   // [1024][66]
  const float* fc_b     = (const float*)d_in[4];   // [66]
  const float* trans    = (const float*)d_in[5];   // [66][66]
  float* outp = (float*)d_out;                     // [0..31]=forward, [32..63]=gold

  // workspace layout
  char* ws = (char*)d_ws;
  float* feats_ws = (float*)ws;                                   //  8,388,608 B
  unsigned short* Wbt = (unsigned short*)(ws + 8388608);          //    131,072 B
  float* chunkP = (float*)(ws + 8388608 + 131072);                // 16,777,216 B
  int* chunkExp = (int*)(ws + 8388608 + 131072 + 16777216);       //      4,096 B

  crf_wcvt<<<16, 256, 0, stream>>>(fc_w, Wbt);
  dim3 cg(32, 32);
  crf_fwd<<<cg, 256, 0, stream>>>(features, Wbt, fc_b, masks, trans,
                                  feats_ws, chunkP, chunkExp);
  crf_fin<<<64, 64, 0, stream>>>(feats_ws, ys, masks, trans, chunkP, chunkExp, outp);
}

// Round 6
// 266.732 us; speedup vs baseline: 1.0938x; 1.0938x over previous
//
#include <hip/hip_runtime.h>
#include <hip/hip_bf16.h>
#include <stdint.h>

// CRF loss (forward partition + gold path score), B=32, L=1024, D=1024, 66 tags.
// Pipeline (3 kernels):
//   crf_wcvt : fc_w [1024][66] fp32 -> Wbt [64][1024] bf16 (LDS-tiled transpose)
//   crf_fwd  : grid (16,32), 4 waves. Per block:
//              (a) emission GEMM 64 rows x 64 tags (bf16 MFMA, global_load_lds
//                  double-buffered staging), raw feats -> ws, exp() -> LDS
//              (b) REGISTER-RESIDENT chunk scan: each wave owns a 64x32 column
//                  slice of the running product P (columns are independent).
//                  Per step: pack P->bf16, build mfma_32x32x16 B-fragments via
//                  v_permlane32_swap (pure-register transpose), 8 MFMA, scale
//                  rows by exp(emit)*2^-ex. NO LDS round-trip, NO barriers.
//              Waves (w>>1) pick chunk cc = 2c+(w>>1) (32 steps); (w&1) picks
//              the column half. Per-wave pow2 exponents -> chunkExp[cc][half].
//   crf_fin  : even blocks: combine (32 chained matvecs, per-half exponent
//              reconciliation, STOP logsumexp); odd blocks: gold path score.
//
// START/STOP tags are exact prob-0 (exp(-10000) underflows to 0 in f32, same
// as the reference) -> live state is exactly 64 tags.

#define START_IDX 64
#define STOP_IDX 65
#define LN2F 0.6931471805599453f

typedef __attribute__((ext_vector_type(4))) float f32x4;
typedef __attribute__((ext_vector_type(16))) float f32x16;
typedef __attribute__((ext_vector_type(8))) __bf16 bf16x8;
typedef __attribute__((ext_vector_type(2))) __bf16 bf16x2;
typedef __attribute__((ext_vector_type(4))) int i32x4;

// async global->LDS, 16B per lane; dst = wave-uniform base + lane*16
__device__ __forceinline__ void gload_lds16(const void* g, void* l) {
  __builtin_amdgcn_global_load_lds(
      (const __attribute__((address_space(1))) void*)g,
      (__attribute__((address_space(3))) void*)l, 16, 0, 0);
}

// pack two f32 into one u32 of 2 bf16 (RNE)
__device__ __forceinline__ int pack_bf16(float lo, float hi) {
  bf16x2 t;
  t[0] = (__bf16)lo;
  t[1] = (__bf16)hi;
  return __builtin_bit_cast(int, t);
}

// v_permlane32_swap_b32: after call x = [x_lo|y_lo], y = [x_hi|y_hi]
__device__ __forceinline__ void pl32_swap(int& x, int& y) {
  asm("v_permlane32_swap_b32 %0, %1" : "+v"(x), "+v"(y));
}

// ------------------------------------------------------------------
// DPP helpers (full-wave reduce; result valid in lane 63; values >= 0)
// ------------------------------------------------------------------
template <int CTRL>
__device__ __forceinline__ float dpp_mov(float v) {
  return __int_as_float(
      __builtin_amdgcn_update_dpp(0, __float_as_int(v), CTRL, 0xF, 0xF, true));
}
__device__ __forceinline__ float wave_max64(float v) {
  v = fmaxf(v, dpp_mov<0xB1>(v));   // quad_perm xor1
  v = fmaxf(v, dpp_mov<0x4E>(v));   // quad_perm xor2
  v = fmaxf(v, dpp_mov<0x141>(v));  // row_half_mirror
  v = fmaxf(v, dpp_mov<0x140>(v));  // row_mirror
  v = fmaxf(v, dpp_mov<0x142>(v));  // row_bcast15
  v = fmaxf(v, dpp_mov<0x143>(v));  // row_bcast31
  return v;
}
__device__ __forceinline__ float wave_sum64(float v) {
  v += dpp_mov<0xB1>(v);
  v += dpp_mov<0x4E>(v);
  v += dpp_mov<0x141>(v);
  v += dpp_mov<0x140>(v);
  v += dpp_mov<0x142>(v);
  v += dpp_mov<0x143>(v);
  return v;
}

// ------------------------------------------------------------------
// W convert+transpose via LDS tile: Wbt[n][k] = bf16(W[k][n]), n<64, k<1024.
// ------------------------------------------------------------------
__global__ __launch_bounds__(256) void crf_wcvt(const float* __restrict__ W,
                                                unsigned short* __restrict__ Wbt) {
  __shared__ float tile[64][65];
  const int t = threadIdx.x;
  const int kb = blockIdx.x;  // k-slice of 64
#pragma unroll
  for (int i = 0; i < 16; ++i) {
    const int f = i * 256 + t;
    const int k = f >> 6, n = f & 63;
    tile[k][n] = W[(kb * 64 + k) * 66 + n];
  }
  __syncthreads();
#pragma unroll
  for (int i = 0; i < 16; ++i) {
    const int f = i * 256 + t;
    const int n = f >> 6, k = f & 63;
    union { __bf16 h; unsigned short u; } cv;
    cv.h = (__bf16)tile[k][n];
    Wbt[n * 1024 + kb * 64 + k] = cv.u;
  }
}

// ------------------------------------------------------------------
// Fused emission GEMM + register-resident chunk scan.
// LDS arena 48KB: As0 [0,16K) As1 [16K,32K) Bs0 [32K,40K) Bs1 [40K,48K);
// expE (float[64][64], 16KB) aliases As0 after the K-loop.
// ------------------------------------------------------------------
__global__ __launch_bounds__(256, 2) void crf_fwd(const float* __restrict__ features,
                                                  const unsigned short* __restrict__ Wbt,
                                                  const float* __restrict__ bias,
                                                  const float* __restrict__ masks,
                                                  const float* __restrict__ trans,
                                                  float* __restrict__ featsOut,
                                                  float* __restrict__ chunkP,
                                                  int* __restrict__ chunkExp) {
  __shared__ __align__(16) char smem[49152];
  const int tid = threadIdx.x;
  const int w = tid >> 6, lane = tid & 63, g = lane >> 4, q = lane & 15;
  const int c = blockIdx.x, b = blockIdx.y;  // c in [0,16): 64-step block

  // ---------- (a) emission GEMM: rows t = 64c+[0,64), cols = 64 tags ----------
  {
    const float* Abase = features + ((size_t)b << 20) + ((size_t)c << 16);
    const int arow0 = 16 * w + (lane >> 4);
    const int acolb = (lane & 15) * 16;
    const int brow0 = 16 * w + (lane >> 3);
    const int bcolb = (lane & 7) * 16;

    f32x4 acc[4];
#pragma unroll
    for (int nt = 0; nt < 4; ++nt) acc[nt] = (f32x4){0.f, 0.f, 0.f, 0.f};

    // prologue: stage tile 0 into buf 0
#pragma unroll
    for (int j = 0; j < 4; ++j) {
      const int row = arow0 + 4 * j;
      gload_lds16((const char*)(Abase + (size_t)row * 1024) +
                      (acolb ^ ((row & 7) << 4)),
                  smem + (16 * w + 4 * j) * 256);
    }
#pragma unroll
    for (int j = 0; j < 2; ++j) {
      const int n = brow0 + 8 * j;
      gload_lds16((const char*)(Wbt + (size_t)n * 1024) +
                      (bcolb ^ ((n & 7) << 4)),
                  smem + 32768 + (16 * w + 8 * j) * 128);
    }

    const int sA = (q & 7) << 4;
    for (int kt = 0; kt < 16; ++kt) {
      const int buf = kt & 1;
      __syncthreads();  // drains vmcnt: buf ready
      if (kt < 15) {    // prefetch next tile into other buffer
        const int k0 = (kt + 1) * 64;
#pragma unroll
        for (int j = 0; j < 4; ++j) {
          const int row = arow0 + 4 * j;
          gload_lds16((const char*)(Abase + (size_t)row * 1024 + k0) +
                          (acolb ^ ((row & 7) << 4)),
                      smem + (buf ^ 1) * 16384 + (16 * w + 4 * j) * 256);
        }
#pragma unroll
        for (int j = 0; j < 2; ++j) {
          const int n = brow0 + 8 * j;
          gload_lds16((const char*)(Wbt + (size_t)n * 1024 + k0) +
                          (bcolb ^ ((n & 7) << 4)),
                      smem + 32768 + (buf ^ 1) * 8192 + (16 * w + 8 * j) * 128);
        }
      }
      const char* Ab = smem + buf * 16384 + (16 * w + q) * 256;
      const char* Bb = smem + 32768 + buf * 8192;
#pragma unroll
      for (int kk = 0; kk < 2; ++kk) {
        float4 alo = *(const float4*)(Ab + ((kk * 128 + 32 * g) ^ sA));
        float4 ahi = *(const float4*)(Ab + ((kk * 128 + 32 * g + 16) ^ sA));
        bf16x8 af;
        af[0] = (__bf16)alo.x; af[1] = (__bf16)alo.y;
        af[2] = (__bf16)alo.z; af[3] = (__bf16)alo.w;
        af[4] = (__bf16)ahi.x; af[5] = (__bf16)ahi.y;
        af[6] = (__bf16)ahi.z; af[7] = (__bf16)ahi.w;
#pragma unroll
        for (int nt = 0; nt < 4; ++nt) {
          const int n = q + 16 * nt;
          bf16x8 bf = *(const bf16x8*)(Bb + n * 128 +
                                       ((kk * 64 + 16 * g) ^ ((n & 7) << 4)));
          acc[nt] = __builtin_amdgcn_mfma_f32_16x16x32_bf16(af, bf, acc[nt], 0, 0, 0);
        }
      }
    }
    // All waves are past the kt=15 barrier -> As0 region free; write expE there.
    const float bb0 = bias[q + 0], bb1 = bias[q + 16];
    const float bb2 = bias[q + 32], bb3 = bias[q + 48];
    float (*expE)[64] = (float(*)[64])smem;
#pragma unroll
    for (int r = 0; r < 4; ++r) {
      const int tl = 16 * w + 4 * g + r;
      float* orow = featsOut + (((size_t)(b << 10) + (c << 6) + tl) << 6) + q;
      const float v0 = acc[0][r] + bb0, v1 = acc[1][r] + bb1;
      const float v2 = acc[2][r] + bb2, v3 = acc[3][r] + bb3;
      orow[0] = v0; orow[16] = v1; orow[32] = v2; orow[48] = v3;
      expE[tl][q + 0]  = __expf(v0);
      expE[tl][q + 16] = __expf(v1);
      expE[tl][q + 32] = __expf(v2);
      expE[tl][q + 48] = __expf(v3);
    }
  }
  __syncthreads();  // expE complete; no barriers after this point

  // ---------- (b) register-resident scan ----------
  const int n32 = lane & 31, H = lane >> 5;
  const int hc = w >> 1;    // which 32-step half of the 64-step block
  const int hcol = w & 1;   // column half owned by this wave
  const int cc = 2 * c + hc;        // global chunk id [0,32)
  const int tbase = cc << 5;

  // E fragments for mfma_32x32x16: A[m][k], m=lane&31, k=8H+e per K-chunk.
  bf16x8 Ea[2][4];
#pragma unroll
  for (int a = 0; a < 2; ++a) {
    const float* tp = trans + (size_t)(32 * a + n32) * 66 + 8 * H;
#pragma unroll
    for (int kc = 0; kc < 4; ++kc)
#pragma unroll
      for (int e = 0; e < 8; ++e)
        Ea[a][kc][e] = (__bf16)__expf(tp[16 * kc + e]);
  }

  // P state: C-layout of 2 tiles (rows 0-31, 32-63) x 32 cols.
  // row(a,r) = 32a + (r&3) + 8*(r>>2) + 4H ; col = 32*hcol + n32.
  float pv[2][16];
#pragma unroll
  for (int a = 0; a < 2; ++a)
#pragma unroll
    for (int r = 0; r < 16; ++r) {
      const int row = 32 * a + (r & 3) + 8 * (r >> 2) + 4 * H;
      pv[a][r] = (row == 32 * hcol + n32) ? 1.f : 0.f;
    }

  const float* mb = masks + (b << 10);
  int tmi = tbase + n32; if (tmi > 1023) tmi = 1023;
  const float mkv = mb[tmi];

  f32x16 zz;
#pragma unroll
  for (int i = 0; i < 16; ++i) zz[i] = 0.f;

  float wmx = 1.f;  // lagged max of pv (power-of-2 rescale source)
  int e_acc = 0;
  float (*expE)[64] = (float(*)[64])smem;
  const int ts0 = (cc == 0) ? 1 : 0;

  for (int ts = ts0; ts < 32; ++ts) {
    const float m =
        __int_as_float(__builtin_amdgcn_readlane(__float_as_int(mkv), ts));
    if (m == 0.f) continue;
    const int tl = (hc << 5) + ts;

    int ex = 0; float sc = 1.f;
    if ((ts & 1) == 0) {  // rescale every 2nd step (growth << fp32 range)
      const int mxb = __builtin_amdgcn_readlane(__float_as_int(wmx), 63);
      ex = ((mxb >> 23) & 0xFF) - 127;
      sc = __int_as_float((127 - ex) << 23);
    }

    // exp(emissions) for this lane's 32 rows: broadcast b128 reads
    f32x4 ce[2][4];
#pragma unroll
    for (int a = 0; a < 2; ++a)
#pragma unroll
      for (int u = 0; u < 4; ++u)
        ce[a][u] = *(const f32x4*)&expE[tl][32 * a + 8 * u + 4 * H];

    // pack P -> bf16 pairs
    int pk0[8], pk1[8];
#pragma unroll
    for (int mi = 0; mi < 8; ++mi) {
      pk0[mi] = pack_bf16(pv[0][2 * mi], pv[0][2 * mi + 1]);
      pk1[mi] = pack_bf16(pv[1][2 * mi], pv[1][2 * mi + 1]);
    }

    // B-fragments via permlane32_swap + 8 MFMA: acc = E . P
    f32x16 a0, a1;
#pragma unroll
    for (int kc = 0; kc < 4; ++kc) {
      int* pks = (kc >> 1) ? pk1 : pk0;
      const int bs = 4 * (kc & 1);
      int x0 = pks[bs + 0], y0 = pks[bs + 2];
      int x1 = pks[bs + 1], y1 = pks[bs + 3];
      pl32_swap(x0, y0);
      pl32_swap(x1, y1);
      i32x4 bi = {x0, x1, y0, y1};
      bf16x8 B = __builtin_bit_cast(bf16x8, bi);
      if (kc == 0) {
        a0 = __builtin_amdgcn_mfma_f32_32x32x16_bf16(Ea[0][0], B, zz, 0, 0, 0);
        a1 = __builtin_amdgcn_mfma_f32_32x32x16_bf16(Ea[1][0], B, zz, 0, 0, 0);
      } else {
        a0 = __builtin_amdgcn_mfma_f32_32x32x16_bf16(Ea[0][kc], B, a0, 0, 0, 0);
        a1 = __builtin_amdgcn_mfma_f32_32x32x16_bf16(Ea[1][kc], B, a1, 0, 0, 0);
      }
    }

    // P' = diag(ce)*acc*sc (+ mask blend), track max for next rescale
    float nmx = 0.f;
    if (m == 1.f) {
#pragma unroll
      for (int u = 0; u < 4; ++u)
#pragma unroll
        for (int vv = 0; vv < 4; ++vv) {
          const int r = 4 * u + vv;
          const float v0 = a0[r] * ce[0][u][vv] * sc;
          const float v1 = a1[r] * ce[1][u][vv] * sc;
          pv[0][r] = v0; pv[1][r] = v1;
          nmx = fmaxf(nmx, fmaxf(v0, v1));
        }
    } else {
#pragma unroll
      for (int u = 0; u < 4; ++u)
#pragma unroll
        for (int vv = 0; vv < 4; ++vv) {
          const int r = 4 * u + vv;
          float v0 = a0[r] * ce[0][u][vv] * sc;
          float v1 = a1[r] * ce[1][u][vv] * sc;
          v0 = m * v0 + (1.f - m) * sc * pv[0][r];
          v1 = m * v1 + (1.f - m) * sc * pv[1][r];
          pv[0][r] = v0; pv[1][r] = v1;
          nmx = fmaxf(nmx, fmaxf(v0, v1));
        }
    }
    if (ts & 1) wmx = wave_max64(nmx);
    e_acc += ex;
  }

  // epilogue: write P slice (fp32) + per-half exponent
  float* Pb = chunkP + (((size_t)(b * 32 + cc)) << 12) + 32 * hcol;
#pragma unroll
  for (int a = 0; a < 2; ++a)
#pragma unroll
    for (int r = 0; r < 16; ++r) {
      const int row = 32 * a + (r & 3) + 8 * (r >> 2) + 4 * H;
      Pb[(size_t)row * 64 + n32] = pv[a][r];
    }
  if (lane == 0) chunkExp[((b * 32 + cc) << 1) + hcol] = e_acc;
}

// ------------------------------------------------------------------
// Final kernel: even blocks -> combine (forward score), odd -> gold score.
// ------------------------------------------------------------------
__global__ void crf_fin(const float* __restrict__ feats,
                        const int* __restrict__ ys,
                        const float* __restrict__ masks,
                        const float* __restrict__ trans,
                        const float* __restrict__ chunkP,
                        const int* __restrict__ chunkExp,
                        float* __restrict__ out) {
  __shared__ __align__(16) float vb[64];
  const int lane = threadIdx.x;
  const int b = blockIdx.x >> 1;
  if ((blockIdx.x & 1) == 0) {
    // ---- combine: v <- Pc . v over 32 chunks (per-half exps), STOP lse ----
    float v = __expf(feats[((size_t)b << 16) + lane]) *
              __expf(trans[lane * 66 + START_IDX]);
    int e_acc = 0;
    for (int cc = 0; cc < 32; ++cc) {
      const int E0 = chunkExp[((b * 32 + cc) << 1)];
      const int E1 = chunkExp[((b * 32 + cc) << 1) + 1];
      const int Em = (E0 > E1) ? E0 : E1;
      int sh = 127 + ((lane < 32) ? E0 : E1) - Em;
      if (sh < 1) sh = 1;
      vb[lane] = v * __int_as_float(sh << 23);
      __builtin_amdgcn_wave_barrier();
      const float* Pr = chunkP + (((size_t)(b * 32 + cc)) << 12) + (size_t)lane * 64;
      float q0 = 0.f, q1 = 0.f, q2 = 0.f, q3 = 0.f;
#pragma unroll
      for (int j4 = 0; j4 < 16; ++j4) {
        float4 p = *(const float4*)(Pr + 4 * j4);
        float4 x = ((const float4*)vb)[j4];
        q0 = fmaf(p.x, x.x, q0); q1 = fmaf(p.y, x.y, q1);
        q2 = fmaf(p.z, x.z, q2); q3 = fmaf(p.w, x.w, q3);
      }
      const float qq = (q0 + q1) + (q2 + q3);
      float mx = wave_max64(qq);
      mx = __int_as_float(__builtin_amdgcn_readlane(__float_as_int(mx), 63));
      const int ex = ((__float_as_int(mx) >> 23) & 0xFF) - 127;
      v = qq * __int_as_float((127 - ex) << 23);
      e_acc += ex + Em;
      __builtin_amdgcn_wave_barrier();
    }
    const float sum = wave_sum64(v * __expf(trans[STOP_IDX * 66 + lane]));
    const float s =
        __int_as_float(__builtin_amdgcn_readlane(__float_as_int(sum), 63));
    if (lane == 0) out[b] = __logf(s) + (float)e_acc * LN2F;
  } else {
    // ---- gold path score ----
    const float* fb = feats + ((size_t)b << 16);
    const float* mb = masks + (b << 10);
    const int* yb = ys + (b << 10);
    float s = 0.f, cnt = 0.f;
#pragma unroll
    for (int cc = 0; cc < 16; ++cc) {
      const int t = cc * 64 + lane;
      const float m = mb[t];
      const int y = yb[t];
      const int yp = (t == 0) ? START_IDX : yb[t - 1];
      s += (trans[y * 66 + yp] + fb[t * 64 + y]) * m;
      cnt += m;
    }
    float tot = wave_sum64(s);
    float len = wave_sum64(cnt);
    int totb = __builtin_amdgcn_readlane(__float_as_int(tot), 63);
    int lenb = __builtin_amdgcn_readlane(__float_as_int(len), 63);
    if (lane == 0) {
      const int Lr = (int)__int_as_float(lenb);
      const int last = (Lr == 0) ? START_IDX : yb[Lr - 1];
      out[32 + b] = __int_as_float(totb) + trans[STOP_IDX * 66 + last];
    }
  }
}

// ------------------------------------------------------------------
extern "C" void kernel_launch(void* const* d_in, const int* in_sizes, int n_in,
                              void* d_out, int out_size, void* d_ws, size_t ws_size,
                              hipStream_t stream) {
  const float* features = (const float*)d_in[0];   // [32][1024][1024]
  const int* ys         = (const int*)d_in[1];     // [32][1024]
  const float* masks    = (const float*)d_in[2];   // [32][1024]
  const float* fc_w     = (const float*)d_in[3];   // [1024][66]
  const float* fc_b     = (const float*)d_in[4];   // [66]
  const float* trans    = (const float*)d_in[5];   // [66][66]
  float* outp = (float*)d_out;                     // [0..31]=forward, [32..63]=gold

  // workspace layout
  char* ws = (char*)d_ws;
  float* feats_ws = (float*)ws;                                   //  8,388,608 B
  unsigned short* Wbt = (unsigned short*)(ws + 8388608);          //    131,072 B
  float* chunkP = (float*)(ws + 8388608 + 131072);                // 16,777,216 B
  int* chunkExp = (int*)(ws + 8388608 + 131072 + 16777216);       //      8,192 B

  crf_wcvt<<<16, 256, 0, stream>>>(fc_w, Wbt);
  dim3 cg(16, 32);
  crf_fwd<<<cg, 256, 0, stream>>>(features, Wbt, fc_b, masks, trans,
                                  feats_ws, chunkP, chunkExp);
  crf_fin<<<64, 64, 0, stream>>>(feats_ws, ys, masks, trans, chunkP, chunkExp, outp);
}